// Round 1
// baseline (2905.013 us; speedup 1.0000x reference)
//
#include <hip/hip_runtime.h>
#include <math.h>

#define NB 16
#define NA 1024
#define NT 512
#define ND 256
#define TWO_D 512

// ---------------- embedding gather ----------------
__global__ void gather_emb_kernel(const int* __restrict__ words,
                                  const float* __restrict__ emb,
                                  float* __restrict__ out, int nrows) {
    int idx = blockIdx.x * 256 + threadIdx.x;
    if (idx >= nrows * 64) return;
    int row = idx >> 6;
    int c4 = (idx & 63) << 2;
    int w = words[row];
    *(float4*)(out + (size_t)row * ND + c4) =
        *(const float4*)(emb + (size_t)w * ND + c4);
}

// ---------------- residual GLU conv block (fused GEMM + GLU + residual) ----
// y[b,l,c] = x[b,l,c] + a*sigmoid(g), where [a;g] = conv1d(x, w, dil) + bias
// w layout: [3][256][512]  (tap, d_in, c_out)
__global__ void __launch_bounds__(256)
conv_glu_kernel(const float* __restrict__ x, float* __restrict__ y,
                const float* __restrict__ w, const float* __restrict__ bias,
                int L, int dil) {
    __shared__ float xs[64][36];   // 64 positions x 32 k-floats (+4 pad, 16B aligned)
    __shared__ float wa[32][64];   // k x c (a-half)
    __shared__ float wg[32][64];   // k x c (g-half)

    int b  = blockIdx.z;
    int l0 = blockIdx.y * 64;
    int c0 = blockIdx.x * 64;      // c0 in {0,64,128,192}; g channels at c0+256
    int tid = threadIdx.x;
    int tx = tid & 15, ty = tid >> 4;

    float acc_a[4][4] = {};
    float acc_g[4][4] = {};

    const float* xb = x + (size_t)b * L * ND;

    int srow = tid >> 2;          // 0..63
    int scol = (tid & 3) << 3;    // 0,8,16,24
    int wrow = tid >> 3;          // 0..31
    int wcol = (tid & 7) << 3;    // 0..56

    for (int tap = 0; tap < 3; ++tap) {
        int shift = (tap - 1) * dil;
        int gp = l0 + srow + shift;
        bool inb = (gp >= 0) && (gp < L);
        const float* xsrc = xb + (size_t)gp * ND + scol;
        const float* wbase = w + ((size_t)tap * ND + wrow) * TWO_D + c0 + wcol;

        for (int k0 = 0; k0 < ND; k0 += 32) {
            // stage x tile
            if (inb) {
                float4 v0 = *(const float4*)(xsrc + k0);
                float4 v1 = *(const float4*)(xsrc + k0 + 4);
                *(float4*)&xs[srow][scol]     = v0;
                *(float4*)&xs[srow][scol + 4] = v1;
            } else {
                float4 z = make_float4(0.f, 0.f, 0.f, 0.f);
                *(float4*)&xs[srow][scol]     = z;
                *(float4*)&xs[srow][scol + 4] = z;
            }
            // stage weight tiles (a-half and g-half)
            const float* wp = wbase + (size_t)k0 * TWO_D;
            *(float4*)&wa[wrow][wcol]     = *(const float4*)(wp);
            *(float4*)&wa[wrow][wcol + 4] = *(const float4*)(wp + 4);
            *(float4*)&wg[wrow][wcol]     = *(const float4*)(wp + 256);
            *(float4*)&wg[wrow][wcol + 4] = *(const float4*)(wp + 260);
            __syncthreads();

            #pragma unroll
            for (int kk = 0; kk < 32; ++kk) {
                float av[4];
                #pragma unroll
                for (int i = 0; i < 4; ++i) av[i] = xs[ty * 4 + i][kk];
                float4 ba4 = *(float4*)&wa[kk][tx * 4];
                float4 bg4 = *(float4*)&wg[kk][tx * 4];
                float bva[4] = {ba4.x, ba4.y, ba4.z, ba4.w};
                float bvg[4] = {bg4.x, bg4.y, bg4.z, bg4.w};
                #pragma unroll
                for (int i = 0; i < 4; ++i) {
                    #pragma unroll
                    for (int j = 0; j < 4; ++j) {
                        acc_a[i][j] = fmaf(av[i], bva[j], acc_a[i][j]);
                        acc_g[i][j] = fmaf(av[i], bvg[j], acc_g[i][j]);
                    }
                }
            }
            __syncthreads();
        }
    }

    // epilogue: GLU + residual
    int r0 = ty * 4;
    int cc0 = tx * 4;
    #pragma unroll
    for (int i = 0; i < 4; ++i) {
        int pos = l0 + r0 + i;
        const float* xr = xb + (size_t)pos * ND + c0 + cc0;
        float* yr = y + ((size_t)b * L + pos) * ND + c0 + cc0;
        #pragma unroll
        for (int j = 0; j < 4; ++j) {
            float av = acc_a[i][j] + bias[c0 + cc0 + j];
            float gv = acc_g[i][j] + bias[c0 + 256 + cc0 + j];
            float sg = 1.f / (1.f + expf(-gv));
            yr[j] = xr[j] + av * sg;
        }
    }
}

// ---------------- row-wise sum of squares ----------------
__global__ void sumsq_kernel(const float* __restrict__ x, float* __restrict__ out,
                             int nrows) {
    int wave = threadIdx.x >> 6;
    int lane = threadIdx.x & 63;
    int row = blockIdx.x * 4 + wave;
    if (row >= nrows) return;
    float4 v = *(const float4*)(x + (size_t)row * ND + lane * 4);
    float s = v.x * v.x + v.y * v.y + v.z * v.z + v.w * v.w;
    #pragma unroll
    for (int off = 32; off; off >>= 1) s += __shfl_down(s, off);
    if (lane == 0) out[row] = s;
}

// ---------------- distance + exp + row max ----------------
__global__ void __launch_bounds__(256)
dist_rowmax_kernel(const float* __restrict__ art, const float* __restrict__ tpl,
                   const float* __restrict__ a2, const float* __restrict__ t2,
                   const float* __restrict__ amask, const float* __restrict__ tmask,
                   float* __restrict__ row_max) {
    __shared__ float as_[64][33];
    __shared__ float ts_[64][33];
    __shared__ float red[64][17];

    int b = blockIdx.y;
    int a0 = blockIdx.x * 64;
    int tid = threadIdx.x;
    int tx = tid & 15, ty = tid >> 4;

    float rmax[4] = {-1e30f, -1e30f, -1e30f, -1e30f};

    const float* ab = art + ((size_t)b * NA + a0) * ND;
    int srow = tid >> 2;
    int scol = (tid & 3) << 3;

    for (int t0 = 0; t0 < NT; t0 += 64) {
        const float* tb = tpl + ((size_t)b * NT + t0) * ND;
        float acc[4][4] = {};
        for (int k0 = 0; k0 < ND; k0 += 32) {
            #pragma unroll
            for (int u = 0; u < 8; ++u) {
                as_[srow][scol + u] = ab[(size_t)srow * ND + k0 + scol + u];
                ts_[srow][scol + u] = tb[(size_t)srow * ND + k0 + scol + u];
            }
            __syncthreads();
            #pragma unroll
            for (int kk = 0; kk < 32; ++kk) {
                float av[4], tv[4];
                #pragma unroll
                for (int i = 0; i < 4; ++i) av[i] = as_[ty * 4 + i][kk];
                #pragma unroll
                for (int j = 0; j < 4; ++j) tv[j] = ts_[tx * 4 + j][kk];
                #pragma unroll
                for (int i = 0; i < 4; ++i)
                    #pragma unroll
                    for (int j = 0; j < 4; ++j)
                        acc[i][j] = fmaf(av[i], tv[j], acc[i][j]);
            }
            __syncthreads();
        }
        #pragma unroll
        for (int i = 0; i < 4; ++i) {
            int a = a0 + ty * 4 + i;
            float a2v = a2[b * NA + a];
            float am = amask[b * NA + a];
            #pragma unroll
            for (int j = 0; j < 4; ++j) {
                int t = t0 + tx * 4 + j;
                float d2 = a2v + t2[b * NT + t] - 2.f * acc[i][j];
                d2 = fmaxf(d2, 0.f);
                float s = expf(-d2) * am * tmask[b * NT + t];
                rmax[i] = fmaxf(rmax[i], s);
            }
        }
        __syncthreads();
    }

    #pragma unroll
    for (int i = 0; i < 4; ++i) red[ty * 4 + i][tx] = rmax[i];
    __syncthreads();
    if (tid < 64) {
        float m = red[tid][0];
        #pragma unroll
        for (int xch = 1; xch < 16; ++xch) m = fmaxf(m, red[tid][xch]);
        row_max[b * NA + a0 + tid] = m;
    }
}

// ---------------- top-10 + MLP ----------------
__global__ void __launch_bounds__(256)
topk_mlp_kernel(const float* __restrict__ row_max,
                const float* __restrict__ ff1_w, const float* __restrict__ ff1_b,
                const float* __restrict__ ff2_w, const float* __restrict__ ff2_b,
                float* __restrict__ out) {
    __shared__ float vals[NA];
    __shared__ float top[10];
    __shared__ float h[10];
    __shared__ float rv[256];
    __shared__ int ri[256];

    int b = blockIdx.x;
    int tid = threadIdx.x;
    for (int i = tid; i < NA; i += 256) vals[i] = row_max[b * NA + i];
    __syncthreads();

    for (int it = 0; it < 10; ++it) {
        float best = -1e30f;
        int bi = 0;
        for (int i = tid; i < NA; i += 256) {
            if (vals[i] > best) { best = vals[i]; bi = i; }
        }
        rv[tid] = best; ri[tid] = bi;
        __syncthreads();
        for (int s = 128; s; s >>= 1) {
            if (tid < s) {
                if (rv[tid + s] > rv[tid]) { rv[tid] = rv[tid + s]; ri[tid] = ri[tid + s]; }
            }
            __syncthreads();
        }
        if (tid == 0) { top[it] = rv[0]; vals[ri[0]] = -1e30f; }
        __syncthreads();
    }

    if (tid < 10) {
        float s = ff1_b[tid];
        #pragma unroll
        for (int i = 0; i < 10; ++i) s += top[i] * ff1_w[i * 10 + tid];
        h[tid] = fmaxf(s, 0.f);
    }
    __syncthreads();
    if (tid == 0) {
        float s = ff2_b[0];
        #pragma unroll
        for (int j = 0; j < 10; ++j) s += h[j] * ff2_w[j];
        out[b] = s;
    }
}

// ---------------- launch ----------------
extern "C" void kernel_launch(void* const* d_in, const int* in_sizes, int n_in,
                              void* d_out, int out_size, void* d_ws, size_t ws_size,
                              hipStream_t stream) {
    const int*   art_w = (const int*)d_in[0];
    const int*   tpl_w = (const int*)d_in[2];
    const float* amask = (const float*)d_in[4];
    const float* tmask = (const float*)d_in[5];
    const float* emb   = (const float*)d_in[6];
    const float* exp_w = (const float*)d_in[7];
    const float* exp_b = (const float*)d_in[8];
    const float* ref_w = (const float*)d_in[9];
    const float* ref_b = (const float*)d_in[10];
    const float* ff1_w = (const float*)d_in[11];
    const float* ff1_b = (const float*)d_in[12];
    const float* ff2_w = (const float*)d_in[13];
    const float* ff2_b = (const float*)d_in[14];
    float* out = (float*)d_out;

    float* ws = (float*)d_ws;
    float* art_a = ws;
    float* art_b = art_a + (size_t)NB * NA * ND;
    float* tpl_a = art_b + (size_t)NB * NA * ND;
    float* tpl_b = tpl_a + (size_t)NB * NT * ND;
    float* a2    = tpl_b + (size_t)NB * NT * ND;
    float* t2    = a2 + NB * NA;
    float* rmax  = t2 + NB * NT;

    gather_emb_kernel<<<(NB * NA * 64 + 255) / 256, 256, 0, stream>>>(art_w, emb, art_a, NB * NA);
    gather_emb_kernel<<<(NB * NT * 64 + 255) / 256, 256, 0, stream>>>(tpl_w, emb, tpl_a, NB * NT);

    const int dils[10] = {1, 2, 4, 8, 16, 32, 32, 1, 1, 1};

    // article encode
    {
        float* cur = art_a; float* nxt = art_b;
        for (int i = 0; i < 10; ++i) {
            const float* w = (i < 7) ? exp_w + (size_t)i * 3 * ND * TWO_D
                                     : ref_w + (size_t)(i - 7) * 3 * ND * TWO_D;
            const float* bb = (i < 7) ? exp_b + (size_t)i * TWO_D
                                      : ref_b + (size_t)(i - 7) * TWO_D;
            conv_glu_kernel<<<dim3(4, NA / 64, NB), 256, 0, stream>>>(cur, nxt, w, bb, NA, dils[i]);
            float* t = cur; cur = nxt; nxt = t;
        }
    }
    // template encode
    {
        float* cur = tpl_a; float* nxt = tpl_b;
        for (int i = 0; i < 10; ++i) {
            const float* w = (i < 7) ? exp_w + (size_t)i * 3 * ND * TWO_D
                                     : ref_w + (size_t)(i - 7) * 3 * ND * TWO_D;
            const float* bb = (i < 7) ? exp_b + (size_t)i * TWO_D
                                      : ref_b + (size_t)(i - 7) * TWO_D;
            conv_glu_kernel<<<dim3(4, NT / 64, NB), 256, 0, stream>>>(cur, nxt, w, bb, NT, dils[i]);
            float* t = cur; cur = nxt; nxt = t;
        }
    }
    // after 10 swaps both end in the *_a buffers
    float* art_fin = art_a;
    float* tpl_fin = tpl_a;

    sumsq_kernel<<<(NB * NA) / 4, 256, 0, stream>>>(art_fin, a2, NB * NA);
    sumsq_kernel<<<(NB * NT) / 4, 256, 0, stream>>>(tpl_fin, t2, NB * NT);

    dist_rowmax_kernel<<<dim3(NA / 64, NB), 256, 0, stream>>>(art_fin, tpl_fin, a2, t2,
                                                              amask, tmask, rmax);

    topk_mlp_kernel<<<NB, 256, 0, stream>>>(rmax, ff1_w, ff1_b, ff2_w, ff2_b, out);
}

// Round 2
// 596.187 us; speedup vs baseline: 4.8727x; 4.8727x over previous
//
#include <hip/hip_runtime.h>
#include <math.h>

#define NB 16
#define NA 1024
#define NT 512
#define ND 256
#define PAD 32

typedef short bf8_t __attribute__((ext_vector_type(8)));
typedef float f4_t __attribute__((ext_vector_type(4)));

__device__ __forceinline__ float bf2f(ushort u) {
    union { unsigned int i; float f; } v; v.i = ((unsigned int)u) << 16; return v.f;
}
__device__ __forceinline__ ushort f2bf(float f) {
    union { float f; unsigned int i; } v; v.f = f;
    unsigned int x = v.i;
    unsigned int r = (x + 0x7fffu + ((x >> 16) & 1u)) >> 16;
    return (ushort)r;
}
__device__ __forceinline__ void gl_lds16(const void* g, void* l) {
    __builtin_amdgcn_global_load_lds(
        (const __attribute__((address_space(1))) unsigned int*)g,
        (__attribute__((address_space(3))) unsigned int*)l, 16, 0, 0);
}

// ---------------- embedding gather (fp32 emb -> bf16 padded act) ------------
__global__ void gather_emb_bf16(const int* __restrict__ words,
                                const float* __restrict__ emb,
                                ushort* __restrict__ out, int L, int n) {
    int idx = blockIdx.x * 256 + threadIdx.x;
    if (idx >= n) return;
    int chunk = idx & 31;          // 8-channel chunk
    int row = idx >> 5;            // global (b,l) row
    int b = row / L, l = row - b * L;
    int wd = words[row];
    const float* src = emb + (size_t)wd * ND + chunk * 8;
    ushort o[8];
    #pragma unroll
    for (int j = 0; j < 8; ++j) o[j] = f2bf(src[j]);
    *(uint4*)(out + ((size_t)b * (L + 2 * PAD) + PAD + l) * ND + chunk * 8) = *(uint4*)o;
}

// ---------------- weight repack: [tap][k][512] fp32 -> [cb][c'][768] bf16 ---
// c' layout per 64-chan block cb: [0,32)=a ch0..31, [32,64)=g ch0..31,
//                                 [64,96)=a ch32..63, [96,128)=g ch32..63
__global__ void __launch_bounds__(256)
repack_w(const float* __restrict__ exp_w, const float* __restrict__ ref_w,
         ushort* __restrict__ wpack) {
    __shared__ float tile[64][65];
    int li = blockIdx.z;
    int r0 = blockIdx.x * 64;          // r = tap*256 + k
    int c0 = blockIdx.y * 64;
    const float* src = (li < 7) ? exp_w + (size_t)li * 3 * ND * 512
                                : ref_w + (size_t)(li - 7) * 3 * ND * 512;
    int tap = r0 >> 8, k0 = r0 & 255;
    int tid = threadIdx.x;
    #pragma unroll
    for (int p = 0; p < 4; ++p) {
        int kr = p * 16 + (tid >> 4);
        int cc = (tid & 15) * 4;
        *(float4*)&tile[kr][cc] =
            *(const float4*)(src + (size_t)(tap * ND + k0 + kr) * 512 + c0 + cc);
    }
    __syncthreads();
    int c_local = tid >> 2;
    int rl0 = (tid & 3) * 16;
    int c = c0 + c_local;
    int half = c >> 8;
    int cc = c & 255;
    int cb = cc >> 6;
    int w64 = cc & 63;
    int cp = ((w64 >> 5) << 6) | (half << 5) | (w64 & 31);
    ushort o[16];
    #pragma unroll
    for (int j = 0; j < 16; ++j) o[j] = f2bf(tile[rl0 + j][c_local]);
    ushort* d = wpack + ((size_t)(li * 4 + cb) * 128 + cp) * 768 + r0 + rl0;
    *(uint4*)d = *(uint4*)o;
    *(uint4*)(d + 8) = *(uint4*)(o + 8);
}

// ---------------- fused conv-GLU-residual, bf16 MFMA ------------------------
// x,y: padded bf16 [B][L+64][256]; wp: [4][128][768] bf16 for this layer
__global__ void __launch_bounds__(256)
conv_glu_mfma(const ushort* __restrict__ x, ushort* __restrict__ y,
              const ushort* __restrict__ wp, const float* __restrict__ bias,
              int L, int dil) {
    __shared__ char smem[32768];
    ushort* Als = (ushort*)smem;            // [128][32] bf16, 8 KB
    ushort* Bls = (ushort*)(smem + 8192);   // [128][32] bf16, 8 KB
    float* ylds = (float*)smem;             // [128][64] fp32, 32 KB (epilogue)

    const int tid = threadIdx.x;
    const int w = tid >> 6, lane = tid & 63;
    const int wm = w >> 1, wn = w & 1;
    const int q = lane >> 4, l15 = lane & 15;

    const int b = blockIdx.z;
    const int l0 = blockIdx.y * 128;
    const int cb = blockIdx.x;

    const size_t bstride = (size_t)(L + 2 * PAD) * ND;
    const ushort* xb = x + (size_t)b * bstride + PAD * ND;   // interior row 0
    ushort* yb = y + (size_t)b * bstride + PAD * ND;
    const ushort* wpc = wp + (size_t)cb * 128 * 768;

    f4_t acc[4][4];
    #pragma unroll
    for (int i = 0; i < 4; ++i)
        #pragma unroll
        for (int j = 0; j < 4; ++j)
            acc[i][j] = (f4_t){0.f, 0.f, 0.f, 0.f};

    const int arow = w * 32;
    const int lrow = lane >> 2;
    const int lcol = (lane & 3) * 8;

    for (int kb = 0; kb < 24; ++kb) {
        const int r0 = kb * 32;
        const int tap = r0 >> 8;
        const int k = r0 & 255;
        const int s = (tap - 1) * dil;
        const ushort* ag = xb + (size_t)(l0 + s + arow + lrow) * ND + k + lcol;
        gl_lds16(ag,            Als + arow * 32);
        gl_lds16(ag + 16 * ND,  Als + (arow + 16) * 32);
        const ushort* bg = wpc + (size_t)(arow + lrow) * 768 + r0 + lcol;
        gl_lds16(bg,            Bls + arow * 32);
        gl_lds16(bg + 16 * 768, Bls + (arow + 16) * 32);
        __syncthreads();

        bf8_t af[4], bfr[4];
        #pragma unroll
        for (int mt = 0; mt < 4; ++mt)
            af[mt] = *(const bf8_t*)(Als + (wm * 64 + mt * 16 + l15) * 32 + q * 8);
        #pragma unroll
        for (int nt = 0; nt < 4; ++nt)
            bfr[nt] = *(const bf8_t*)(Bls + (wn * 64 + nt * 16 + l15) * 32 + q * 8);
        #pragma unroll
        for (int mt = 0; mt < 4; ++mt)
            #pragma unroll
            for (int nt = 0; nt < 4; ++nt)
                acc[mt][nt] = __builtin_amdgcn_mfma_f32_16x16x32_bf16(
                    af[mt], bfr[nt], acc[mt][nt], 0, 0, 0);
        __syncthreads();
    }

    // GLU epilogue into LDS (fp32), channels local [0,64)
    #pragma unroll
    for (int nt = 0; nt < 2; ++nt) {
        const int cl = wn * 32 + nt * 16 + l15;
        const int chan = cb * 64 + cl;
        const float ba = bias[chan];
        const float bg2 = bias[chan + 256];
        #pragma unroll
        for (int mt = 0; mt < 4; ++mt) {
            #pragma unroll
            for (int r = 0; r < 4; ++r) {
                const int row = wm * 64 + mt * 16 + q * 4 + r;
                float av = acc[mt][nt][r] + ba;
                float gv = acc[mt][nt + 2][r] + bg2;
                ylds[row * 64 + cl] = av / (1.f + __expf(-gv));
            }
        }
    }
    __syncthreads();

    // residual add + bf16 store, coalesced 128B rows
    #pragma unroll
    for (int p = 0; p < 4; ++p) {
        int gi = p * 256 + tid;
        int row = gi >> 3;
        int cs = (gi & 7) * 8;
        const ushort* xr = xb + (size_t)(l0 + row) * ND + cb * 64 + cs;
        ushort xv[8]; *(uint4*)xv = *(const uint4*)xr;
        ushort ov[8];
        #pragma unroll
        for (int j = 0; j < 8; ++j)
            ov[j] = f2bf(bf2f(xv[j]) + ylds[row * 64 + cs + j]);
        *(uint4*)(yb + (size_t)(l0 + row) * ND + cb * 64 + cs) = *(uint4*)ov;
    }
}

// ---------------- row-wise sum of squares (bf16 padded input) ---------------
__global__ void sumsq_bf16(const ushort* __restrict__ x, float* __restrict__ out,
                           int L, int nrows) {
    int wv = threadIdx.x >> 6, lane = threadIdx.x & 63;
    int row = blockIdx.x * 4 + wv;
    if (row >= nrows) return;
    int b = row / L, l = row - b * L;
    const ushort* p = x + ((size_t)b * (L + 2 * PAD) + PAD + l) * ND + lane * 4;
    ushort v[4]; *(uint2*)v = *(const uint2*)p;
    float s = 0.f;
    #pragma unroll
    for (int j = 0; j < 4; ++j) { float f = bf2f(v[j]); s += f * f; }
    #pragma unroll
    for (int off = 32; off; off >>= 1) s += __shfl_down(s, off);
    if (lane == 0) out[row] = s;
}

// ---------------- distance + exp + row max, bf16 MFMA -----------------------
__global__ void __launch_bounds__(256)
dist_rowmax_mfma(const ushort* __restrict__ art, const ushort* __restrict__ tpl,
                 const float* __restrict__ a2, const float* __restrict__ t2,
                 const float* __restrict__ amask, const float* __restrict__ tmask,
                 float* __restrict__ rmaxp) {
    __shared__ ushort Als[128 * 32];
    __shared__ ushort Bls[128 * 32];
    __shared__ float red[2][128];

    const int tid = threadIdx.x;
    const int w = tid >> 6, lane = tid & 63;
    const int wm = w >> 1, wn = w & 1;
    const int q = lane >> 4, l15 = lane & 15;

    const int b = blockIdx.y;
    const int a0 = blockIdx.x * 128;
    const int t0 = blockIdx.z * 128;

    const ushort* ab = art + ((size_t)b * (NA + 2 * PAD) + PAD) * ND;
    const ushort* tb = tpl + ((size_t)b * (NT + 2 * PAD) + PAD) * ND;

    float a2v[4][4], amv[4][4];
    #pragma unroll
    for (int mt = 0; mt < 4; ++mt)
        #pragma unroll
        for (int r = 0; r < 4; ++r) {
            int row = a0 + wm * 64 + mt * 16 + q * 4 + r;
            a2v[mt][r] = a2[b * NA + row];
            amv[mt][r] = amask[b * NA + row];
        }

    f4_t acc[4][4];
    #pragma unroll
    for (int i = 0; i < 4; ++i)
        #pragma unroll
        for (int j = 0; j < 4; ++j)
            acc[i][j] = (f4_t){0.f, 0.f, 0.f, 0.f};

    const int arow = w * 32;
    const int lrow = lane >> 2;
    const int lcol = (lane & 3) * 8;

    for (int kb = 0; kb < 8; ++kb) {
        const int k = kb * 32;
        const ushort* ag = ab + (size_t)(a0 + arow + lrow) * ND + k + lcol;
        gl_lds16(ag,           Als + arow * 32);
        gl_lds16(ag + 16 * ND, Als + (arow + 16) * 32);
        const ushort* bg = tb + (size_t)(t0 + arow + lrow) * ND + k + lcol;
        gl_lds16(bg,           Bls + arow * 32);
        gl_lds16(bg + 16 * ND, Bls + (arow + 16) * 32);
        __syncthreads();

        bf8_t af[4], bfr[4];
        #pragma unroll
        for (int mt = 0; mt < 4; ++mt)
            af[mt] = *(const bf8_t*)(Als + (wm * 64 + mt * 16 + l15) * 32 + q * 8);
        #pragma unroll
        for (int nt = 0; nt < 4; ++nt)
            bfr[nt] = *(const bf8_t*)(Bls + (wn * 64 + nt * 16 + l15) * 32 + q * 8);
        #pragma unroll
        for (int mt = 0; mt < 4; ++mt)
            #pragma unroll
            for (int nt = 0; nt < 4; ++nt)
                acc[mt][nt] = __builtin_amdgcn_mfma_f32_16x16x32_bf16(
                    af[mt], bfr[nt], acc[mt][nt], 0, 0, 0);
        __syncthreads();
    }

    float rm[4][4];
    #pragma unroll
    for (int mt = 0; mt < 4; ++mt)
        #pragma unroll
        for (int r = 0; r < 4; ++r) rm[mt][r] = 0.f;

    #pragma unroll
    for (int nt = 0; nt < 4; ++nt) {
        int t = t0 + wn * 64 + nt * 16 + l15;
        float t2v = t2[b * NT + t];
        float tmv = tmask[b * NT + t];
        #pragma unroll
        for (int mt = 0; mt < 4; ++mt)
            #pragma unroll
            for (int r = 0; r < 4; ++r) {
                float d = a2v[mt][r] + t2v - 2.f * acc[mt][nt][r];
                d = fmaxf(d, 0.f);
                float s = __expf(-d) * amv[mt][r] * tmv;
                rm[mt][r] = fmaxf(rm[mt][r], s);
            }
    }
    #pragma unroll
    for (int mt = 0; mt < 4; ++mt)
        #pragma unroll
        for (int r = 0; r < 4; ++r) {
            float v = rm[mt][r];
            #pragma unroll
            for (int off = 1; off < 16; off <<= 1)
                v = fmaxf(v, __shfl_xor(v, off));
            rm[mt][r] = v;
        }
    if (l15 == 0) {
        #pragma unroll
        for (int mt = 0; mt < 4; ++mt)
            #pragma unroll
            for (int r = 0; r < 4; ++r)
                red[wn][wm * 64 + mt * 16 + q * 4 + r] = rm[mt][r];
    }
    __syncthreads();
    if (tid < 128)
        rmaxp[((size_t)blockIdx.z * NB + b) * NA + a0 + tid] =
            fmaxf(red[0][tid], red[1][tid]);
}

// ---------------- top-10 + MLP ----------------------------------------------
__global__ void __launch_bounds__(256)
topk_mlp_kernel(const float* __restrict__ rmaxp,
                const float* __restrict__ ff1_w, const float* __restrict__ ff1_b,
                const float* __restrict__ ff2_w, const float* __restrict__ ff2_b,
                float* __restrict__ out) {
    __shared__ float vals[NA];
    __shared__ float top[10];
    __shared__ float h[10];
    __shared__ float rv[256];
    __shared__ int ri[256];

    int b = blockIdx.x;
    int tid = threadIdx.x;
    for (int i = tid; i < NA; i += 256) {
        float m = rmaxp[(size_t)b * NA + i];
        m = fmaxf(m, rmaxp[((size_t)NB + b) * NA + i]);
        m = fmaxf(m, rmaxp[((size_t)2 * NB + b) * NA + i]);
        m = fmaxf(m, rmaxp[((size_t)3 * NB + b) * NA + i]);
        vals[i] = m;
    }
    __syncthreads();

    for (int it = 0; it < 10; ++it) {
        float best = -1e30f;
        int bi = 0;
        for (int i = tid; i < NA; i += 256) {
            if (vals[i] > best) { best = vals[i]; bi = i; }
        }
        rv[tid] = best; ri[tid] = bi;
        __syncthreads();
        for (int s = 128; s; s >>= 1) {
            if (tid < s) {
                if (rv[tid + s] > rv[tid]) { rv[tid] = rv[tid + s]; ri[tid] = ri[tid + s]; }
            }
            __syncthreads();
        }
        if (tid == 0) { top[it] = rv[0]; vals[ri[0]] = -1e30f; }
        __syncthreads();
    }

    if (tid < 10) {
        float s = ff1_b[tid];
        #pragma unroll
        for (int i = 0; i < 10; ++i) s += top[i] * ff1_w[i * 10 + tid];
        h[tid] = fmaxf(s, 0.f);
    }
    __syncthreads();
    if (tid == 0) {
        float s = ff2_b[0];
        #pragma unroll
        for (int j = 0; j < 10; ++j) s += h[j] * ff2_w[j];
        out[b] = s;
    }
}

// ---------------- launch ----------------------------------------------------
extern "C" void kernel_launch(void* const* d_in, const int* in_sizes, int n_in,
                              void* d_out, int out_size, void* d_ws, size_t ws_size,
                              hipStream_t stream) {
    const int*   art_w = (const int*)d_in[0];
    const int*   tpl_w = (const int*)d_in[2];
    const float* amask = (const float*)d_in[4];
    const float* tmask = (const float*)d_in[5];
    const float* emb   = (const float*)d_in[6];
    const float* exp_w = (const float*)d_in[7];
    const float* exp_b = (const float*)d_in[8];
    const float* ref_w = (const float*)d_in[9];
    const float* ref_b = (const float*)d_in[10];
    const float* ff1_w = (const float*)d_in[11];
    const float* ff1_b = (const float*)d_in[12];
    const float* ff2_w = (const float*)d_in[13];
    const float* ff2_b = (const float*)d_in[14];
    float* out = (float*)d_out;

    const size_t art_bytes = (size_t)NB * (NA + 2 * PAD) * ND * 2;   // 8.9 MB
    const size_t tpl_bytes = (size_t)NB * (NT + 2 * PAD) * ND * 2;   // 4.7 MB
    const size_t wpk_bytes = (size_t)10 * 4 * 128 * 768 * 2;         // 7.9 MB

    char* p = (char*)d_ws;
    ushort* art_a = (ushort*)p; p += art_bytes;
    ushort* art_b = (ushort*)p; p += art_bytes;
    ushort* tpl_a = (ushort*)p; p += tpl_bytes;
    ushort* tpl_b = (ushort*)p; p += tpl_bytes;
    ushort* wpack = (ushort*)p; p += wpk_bytes;
    float* a2    = (float*)p; p += (size_t)NB * NA * 4;
    float* t2    = (float*)p; p += (size_t)NB * NT * 4;
    float* rmaxp = (float*)p; p += (size_t)4 * NB * NA * 4;

    // zero pads (interior gets overwritten by gather/conv)
    hipMemsetAsync(art_a, 0, art_bytes, stream);
    hipMemsetAsync(art_b, 0, art_bytes, stream);
    hipMemsetAsync(tpl_a, 0, tpl_bytes, stream);
    hipMemsetAsync(tpl_b, 0, tpl_bytes, stream);

    repack_w<<<dim3(12, 8, 10), 256, 0, stream>>>(exp_w, ref_w, wpack);

    {
        int n = NB * NA * 32;
        gather_emb_bf16<<<(n + 255) / 256, 256, 0, stream>>>(art_w, emb, art_a, NA, n);
        n = NB * NT * 32;
        gather_emb_bf16<<<(n + 255) / 256, 256, 0, stream>>>(tpl_w, emb, tpl_a, NT, n);
    }

    const int dils[10] = {1, 2, 4, 8, 16, 32, 32, 1, 1, 1};

    {
        ushort* cur = art_a; ushort* nxt = art_b;
        for (int i = 0; i < 10; ++i) {
            const ushort* wl = wpack + (size_t)i * 4 * 128 * 768;
            const float* bb = (i < 7) ? exp_b + (size_t)i * 512
                                      : ref_b + (size_t)(i - 7) * 512;
            conv_glu_mfma<<<dim3(4, NA / 128, NB), 256, 0, stream>>>(cur, nxt, wl, bb, NA, dils[i]);
            ushort* t = cur; cur = nxt; nxt = t;
        }
    }
    {
        ushort* cur = tpl_a; ushort* nxt = tpl_b;
        for (int i = 0; i < 10; ++i) {
            const ushort* wl = wpack + (size_t)i * 4 * 128 * 768;
            const float* bb = (i < 7) ? exp_b + (size_t)i * 512
                                      : ref_b + (size_t)(i - 7) * 512;
            conv_glu_mfma<<<dim3(4, NT / 128, NB), 256, 0, stream>>>(cur, nxt, wl, bb, NT, dils[i]);
            ushort* t = cur; cur = nxt; nxt = t;
        }
    }
    ushort* art_fin = art_a;   // 10 swaps -> back to _a
    ushort* tpl_fin = tpl_a;

    sumsq_bf16<<<(NB * NA) / 4, 256, 0, stream>>>(art_fin, a2, NA, NB * NA);
    sumsq_bf16<<<(NB * NT) / 4, 256, 0, stream>>>(tpl_fin, t2, NT, NB * NT);

    dist_rowmax_mfma<<<dim3(NA / 128, NB, 4), 256, 0, stream>>>(
        art_fin, tpl_fin, a2, t2, amask, tmask, rmaxp);

    topk_mlp_kernel<<<NB, 256, 0, stream>>>(rmaxp, ff1_w, ff1_b, ff2_w, ff2_b, out);
}

// Round 3
// 557.539 us; speedup vs baseline: 5.2104x; 1.0693x over previous
//
#include <hip/hip_runtime.h>
#include <math.h>

#define NB 16
#define NA 1024
#define NT 512
#define ND 256
#define PAD 32

typedef short bf8_t __attribute__((ext_vector_type(8)));
typedef float f4_t __attribute__((ext_vector_type(4)));

__device__ __forceinline__ float bf2f(ushort u) {
    union { unsigned int i; float f; } v; v.i = ((unsigned int)u) << 16; return v.f;
}
__device__ __forceinline__ ushort f2bf(float f) {
    union { float f; unsigned int i; } v; v.f = f;
    unsigned int x = v.i;
    unsigned int r = (x + 0x7fffu + ((x >> 16) & 1u)) >> 16;
    return (ushort)r;
}
__device__ __forceinline__ void gl_lds16(const void* g, void* l) {
    __builtin_amdgcn_global_load_lds(
        (const __attribute__((address_space(1))) unsigned int*)g,
        (__attribute__((address_space(3))) unsigned int*)l, 16, 0, 0);
}

// ---------------- zero only the pad rows of the 4 activation buffers --------
__global__ void pad_zero(ushort* __restrict__ art_a, ushort* __restrict__ art_b,
                         ushort* __restrict__ tpl_a, ushort* __restrict__ tpl_b) {
    int y = blockIdx.y;
    ushort* p = (y == 0) ? art_a : (y == 1) ? art_b : (y == 2) ? tpl_a : tpl_b;
    int L = (y < 2) ? NA : NT;
    int idx = blockIdx.x * 256 + threadIdx.x;
    if (idx >= NB * 64 * 32) return;
    int b = idx >> 11;
    int rem = idx & 2047;
    int row_in = rem >> 5;                 // 0..63
    int ch = (rem & 31) * 8;
    int slab_row = (row_in < 32) ? row_in : L + row_in;   // front / back pad
    uint4 z = make_uint4(0, 0, 0, 0);
    *(uint4*)(p + ((size_t)b * (L + 2 * PAD) + slab_row) * ND + ch) = z;
}

// ---------------- embedding gather (fp32 emb -> bf16 padded act) ------------
__global__ void gather_emb_bf16(const int* __restrict__ words,
                                const float* __restrict__ emb,
                                ushort* __restrict__ out, int L, int n) {
    int idx = blockIdx.x * 256 + threadIdx.x;
    if (idx >= n) return;
    int chunk = idx & 31;
    int row = idx >> 5;
    int b = row / L, l = row - b * L;
    int wd = words[row];
    const float* src = emb + (size_t)wd * ND + chunk * 8;
    ushort o[8];
    #pragma unroll
    for (int j = 0; j < 8; ++j) o[j] = f2bf(src[j]);
    *(uint4*)(out + ((size_t)b * (L + 2 * PAD) + PAD + l) * ND + chunk * 8) = *(uint4*)o;
}

// ---------------- weight repack: fp32 [tap][k][512] -> bf16 [cb][c'][768] ---
__global__ void __launch_bounds__(256)
repack_w(const float* __restrict__ exp_w, const float* __restrict__ ref_w,
         ushort* __restrict__ wpack) {
    __shared__ float tile[64][65];
    int li = blockIdx.z;
    int r0 = blockIdx.x * 64;
    int c0 = blockIdx.y * 64;
    const float* src = (li < 7) ? exp_w + (size_t)li * 3 * ND * 512
                                : ref_w + (size_t)(li - 7) * 3 * ND * 512;
    int tap = r0 >> 8, k0 = r0 & 255;
    int tid = threadIdx.x;
    #pragma unroll
    for (int p = 0; p < 4; ++p) {
        int kr = p * 16 + (tid >> 4);
        int cc = (tid & 15) * 4;
        *(float4*)&tile[kr][cc] =
            *(const float4*)(src + (size_t)(tap * ND + k0 + kr) * 512 + c0 + cc);
    }
    __syncthreads();
    int c_local = tid >> 2;
    int rl0 = (tid & 3) * 16;
    int c = c0 + c_local;
    int half = c >> 8;
    int cc = c & 255;
    int cb = cc >> 6;
    int w64 = cc & 63;
    int cp = ((w64 >> 5) << 6) | (half << 5) | (w64 & 31);
    ushort o[16];
    #pragma unroll
    for (int j = 0; j < 16; ++j) o[j] = f2bf(tile[rl0 + j][c_local]);
    ushort* d = wpack + ((size_t)(li * 4 + cb) * 128 + cp) * 768 + r0 + rl0;
    *(uint4*)d = *(uint4*)o;
    *(uint4*)(d + 8) = *(uint4*)(o + 8);
}

// ---------------- fused conv-GLU-residual, bf16 MFMA (art+tpl fused) --------
// A slab staged once per 32-k chunk covering all 3 tap shifts (192 rows);
// A/B in LDS k-chunk-major so ds_read_b128 frag reads are conflict-free.
__global__ void __launch_bounds__(256, 3)
conv_glu_mfma(const ushort* __restrict__ art_x, ushort* __restrict__ art_y,
              const ushort* __restrict__ tpl_x, ushort* __restrict__ tpl_y,
              const ushort* __restrict__ wp, const float* __restrict__ bias,
              int dil) {
    __shared__ char smem[36864];
    ushort* Als = (ushort*)smem;            // 12 KB: chunk n = q*192 + r, r=0..191
    ushort* Bls = (ushort*)(smem + 12288);  // 24 KB: tap t, chunk n = q*128 + c'
    float* ylds = (float*)smem;             // 32 KB epilogue (reuses A/B)

    const int tid = threadIdx.x;
    const int w = tid >> 6, lane = tid & 63;
    const int wm = w >> 1, wn = w & 1;
    const int q = lane >> 4, l15 = lane & 15;

    const int b = blockIdx.z;
    const int plane = blockIdx.y;
    const int cb = blockIdx.x;

    int L, l0;
    const ushort* xb;
    ushort* yb;
    if (plane < 8) {
        L = NA; l0 = plane * 128;
        xb = art_x + ((size_t)b * (NA + 2 * PAD) + PAD) * ND;
        yb = art_y + ((size_t)b * (NA + 2 * PAD) + PAD) * ND;
    } else {
        L = NT; l0 = (plane - 8) * 128;
        xb = tpl_x + ((size_t)b * (NT + 2 * PAD) + PAD) * ND;
        yb = tpl_y + ((size_t)b * (NT + 2 * PAD) + PAD) * ND;
    }
    const ushort* wpc = wp + (size_t)cb * 128 * 768;

    f4_t acc[4][4];
    #pragma unroll
    for (int i = 0; i < 4; ++i)
        #pragma unroll
        for (int j = 0; j < 4; ++j)
            acc[i][j] = (f4_t){0.f, 0.f, 0.f, 0.f};

    for (int kc = 0; kc < 8; ++kc) {
        const int k0 = kc * 32;
        // --- stage A_ext: 192 rows (l0-32 .. l0+159), k-chunk-major ---
        #pragma unroll
        for (int s3 = 0; s3 < 3; ++s3) {
            int s = w + s3 * 4;              // 0..11
            int qq = s / 3;
            int r = (s % 3) * 64 + lane;
            const ushort* g = xb + (size_t)(l0 - 32 + r) * ND + k0 + qq * 8;
            gl_lds16(g, Als + s * 512);
        }
        // --- stage B: 3 taps x 128 c' x 32 k, k-chunk-major per tap ---
        #pragma unroll
        for (int s3 = 0; s3 < 6; ++s3) {
            int s = w + s3 * 4;              // 0..23
            int t = s >> 3;
            int sp = s & 7;
            int qq = sp >> 1;
            int cp = (sp & 1) * 64 + lane;
            const ushort* g = wpc + (size_t)cp * 768 + t * 256 + k0 + qq * 8;
            gl_lds16(g, Bls + s * 512);
        }
        __syncthreads();

        #pragma unroll
        for (int t = 0; t < 3; ++t) {
            const int sh = (t - 1) * dil;
            bf8_t af[4], bfr[4];
            #pragma unroll
            for (int mt = 0; mt < 4; ++mt)
                af[mt] = *(const bf8_t*)(Als + q * 1536 +
                         (32 + sh + wm * 64 + mt * 16 + l15) * 8);
            #pragma unroll
            for (int nt = 0; nt < 4; ++nt)
                bfr[nt] = *(const bf8_t*)(Bls + t * 4096 + q * 1024 +
                          (wn * 64 + nt * 16 + l15) * 8);
            #pragma unroll
            for (int mt = 0; mt < 4; ++mt)
                #pragma unroll
                for (int nt = 0; nt < 4; ++nt)
                    acc[mt][nt] = __builtin_amdgcn_mfma_f32_16x16x32_bf16(
                        af[mt], bfr[nt], acc[mt][nt], 0, 0, 0);
        }
        __syncthreads();
    }

    // GLU epilogue into LDS (fp32)
    #pragma unroll
    for (int nt = 0; nt < 2; ++nt) {
        const int cl = wn * 32 + nt * 16 + l15;
        const int chan = cb * 64 + cl;
        const float ba = bias[chan];
        const float bg2 = bias[chan + 256];
        #pragma unroll
        for (int mt = 0; mt < 4; ++mt) {
            #pragma unroll
            for (int r = 0; r < 4; ++r) {
                const int row = wm * 64 + mt * 16 + q * 4 + r;
                float av = acc[mt][nt][r] + ba;
                float gv = acc[mt][nt + 2][r] + bg2;
                ylds[row * 64 + cl] = av / (1.f + __expf(-gv));
            }
        }
    }
    __syncthreads();

    // residual add + bf16 store
    #pragma unroll
    for (int p = 0; p < 4; ++p) {
        int gi = p * 256 + tid;
        int row = gi >> 3;
        int cs = (gi & 7) * 8;
        const ushort* xr = xb + (size_t)(l0 + row) * ND + cb * 64 + cs;
        ushort xv[8]; *(uint4*)xv = *(const uint4*)xr;
        ushort ov[8];
        #pragma unroll
        for (int j = 0; j < 8; ++j)
            ov[j] = f2bf(bf2f(xv[j]) + ylds[row * 64 + cs + j]);
        *(uint4*)(yb + (size_t)(l0 + row) * ND + cb * 64 + cs) = *(uint4*)ov;
    }
}

// ---------------- row-wise sum of squares -----------------------------------
__global__ void sumsq_bf16(const ushort* __restrict__ x, float* __restrict__ out,
                           int L, int nrows) {
    int wv = threadIdx.x >> 6, lane = threadIdx.x & 63;
    int row = blockIdx.x * 4 + wv;
    if (row >= nrows) return;
    int b = row / L, l = row - b * L;
    const ushort* p = x + ((size_t)b * (L + 2 * PAD) + PAD + l) * ND + lane * 4;
    ushort v[4]; *(uint2*)v = *(const uint2*)p;
    float s = 0.f;
    #pragma unroll
    for (int j = 0; j < 4; ++j) { float f = bf2f(v[j]); s += f * f; }
    #pragma unroll
    for (int off = 32; off; off >>= 1) s += __shfl_down(s, off);
    if (lane == 0) out[row] = s;
}

// ---------------- distance + exp + row max, bf16 MFMA -----------------------
__global__ void __launch_bounds__(256)
dist_rowmax_mfma(const ushort* __restrict__ art, const ushort* __restrict__ tpl,
                 const float* __restrict__ a2, const float* __restrict__ t2,
                 const float* __restrict__ amask, const float* __restrict__ tmask,
                 float* __restrict__ rmaxp) {
    __shared__ ushort Als[128 * 32];   // chunk n = q*128 + r (k-chunk-major)
    __shared__ ushort Bls[128 * 32];
    __shared__ float red[2][128];

    const int tid = threadIdx.x;
    const int w = tid >> 6, lane = tid & 63;
    const int wm = w >> 1, wn = w & 1;
    const int q = lane >> 4, l15 = lane & 15;

    const int b = blockIdx.y;
    const int a0 = blockIdx.x * 128;
    const int t0 = blockIdx.z * 128;

    const ushort* ab = art + ((size_t)b * (NA + 2 * PAD) + PAD) * ND;
    const ushort* tb = tpl + ((size_t)b * (NT + 2 * PAD) + PAD) * ND;

    float a2v[4][4], amv[4][4];
    #pragma unroll
    for (int mt = 0; mt < 4; ++mt)
        #pragma unroll
        for (int r = 0; r < 4; ++r) {
            int row = a0 + wm * 64 + mt * 16 + q * 4 + r;
            a2v[mt][r] = a2[b * NA + row];
            amv[mt][r] = amask[b * NA + row];
        }

    f4_t acc[4][4];
    #pragma unroll
    for (int i = 0; i < 4; ++i)
        #pragma unroll
        for (int j = 0; j < 4; ++j)
            acc[i][j] = (f4_t){0.f, 0.f, 0.f, 0.f};

    for (int kb = 0; kb < 8; ++kb) {
        const int k0 = kb * 32;
        #pragma unroll
        for (int s3 = 0; s3 < 2; ++s3) {
            int s = w + s3 * 4;              // 0..7
            int qq = s >> 1;
            int r = (s & 1) * 64 + lane;
            gl_lds16(ab + (size_t)(a0 + r) * ND + k0 + qq * 8, Als + s * 512);
            gl_lds16(tb + (size_t)(t0 + r) * ND + k0 + qq * 8, Bls + s * 512);
        }
        __syncthreads();

        bf8_t af[4], bfr[4];
        #pragma unroll
        for (int mt = 0; mt < 4; ++mt)
            af[mt] = *(const bf8_t*)(Als + q * 1024 + (wm * 64 + mt * 16 + l15) * 8);
        #pragma unroll
        for (int nt = 0; nt < 4; ++nt)
            bfr[nt] = *(const bf8_t*)(Bls + q * 1024 + (wn * 64 + nt * 16 + l15) * 8);
        #pragma unroll
        for (int mt = 0; mt < 4; ++mt)
            #pragma unroll
            for (int nt = 0; nt < 4; ++nt)
                acc[mt][nt] = __builtin_amdgcn_mfma_f32_16x16x32_bf16(
                    af[mt], bfr[nt], acc[mt][nt], 0, 0, 0);
        __syncthreads();
    }

    float rm[4][4];
    #pragma unroll
    for (int mt = 0; mt < 4; ++mt)
        #pragma unroll
        for (int r = 0; r < 4; ++r) rm[mt][r] = 0.f;

    #pragma unroll
    for (int nt = 0; nt < 4; ++nt) {
        int t = t0 + wn * 64 + nt * 16 + l15;
        float t2v = t2[b * NT + t];
        float tmv = tmask[b * NT + t];
        #pragma unroll
        for (int mt = 0; mt < 4; ++mt)
            #pragma unroll
            for (int r = 0; r < 4; ++r) {
                float d = a2v[mt][r] + t2v - 2.f * acc[mt][nt][r];
                d = fmaxf(d, 0.f);
                float s = __expf(-d) * amv[mt][r] * tmv;
                rm[mt][r] = fmaxf(rm[mt][r], s);
            }
    }
    #pragma unroll
    for (int mt = 0; mt < 4; ++mt)
        #pragma unroll
        for (int r = 0; r < 4; ++r) {
            float v = rm[mt][r];
            #pragma unroll
            for (int off = 1; off < 16; off <<= 1)
                v = fmaxf(v, __shfl_xor(v, off));
            rm[mt][r] = v;
        }
    if (l15 == 0) {
        #pragma unroll
        for (int mt = 0; mt < 4; ++mt)
            #pragma unroll
            for (int r = 0; r < 4; ++r)
                red[wn][wm * 64 + mt * 16 + q * 4 + r] = rm[mt][r];
    }
    __syncthreads();
    if (tid < 128)
        rmaxp[((size_t)blockIdx.z * NB + b) * NA + a0 + tid] =
            fmaxf(red[0][tid], red[1][tid]);
}

// ---------------- top-10 + MLP ----------------------------------------------
__global__ void __launch_bounds__(256)
topk_mlp_kernel(const float* __restrict__ rmaxp,
                const float* __restrict__ ff1_w, const float* __restrict__ ff1_b,
                const float* __restrict__ ff2_w, const float* __restrict__ ff2_b,
                float* __restrict__ out) {
    __shared__ float vals[NA];
    __shared__ float top[10];
    __shared__ float h[10];
    __shared__ float rv[256];
    __shared__ int ri[256];

    int b = blockIdx.x;
    int tid = threadIdx.x;
    for (int i = tid; i < NA; i += 256) {
        float m = rmaxp[(size_t)b * NA + i];
        m = fmaxf(m, rmaxp[((size_t)NB + b) * NA + i]);
        m = fmaxf(m, rmaxp[((size_t)2 * NB + b) * NA + i]);
        m = fmaxf(m, rmaxp[((size_t)3 * NB + b) * NA + i]);
        vals[i] = m;
    }
    __syncthreads();

    for (int it = 0; it < 10; ++it) {
        float best = -1e30f;
        int bi = 0;
        for (int i = tid; i < NA; i += 256) {
            if (vals[i] > best) { best = vals[i]; bi = i; }
        }
        rv[tid] = best; ri[tid] = bi;
        __syncthreads();
        for (int s = 128; s; s >>= 1) {
            if (tid < s) {
                if (rv[tid + s] > rv[tid]) { rv[tid] = rv[tid + s]; ri[tid] = ri[tid + s]; }
            }
            __syncthreads();
        }
        if (tid == 0) { top[it] = rv[0]; vals[ri[0]] = -1e30f; }
        __syncthreads();
    }

    if (tid < 10) {
        float s = ff1_b[tid];
        #pragma unroll
        for (int i = 0; i < 10; ++i) s += top[i] * ff1_w[i * 10 + tid];
        h[tid] = fmaxf(s, 0.f);
    }
    __syncthreads();
    if (tid == 0) {
        float s = ff2_b[0];
        #pragma unroll
        for (int j = 0; j < 10; ++j) s += h[j] * ff2_w[j];
        out[b] = s;
    }
}

// ---------------- launch ----------------------------------------------------
extern "C" void kernel_launch(void* const* d_in, const int* in_sizes, int n_in,
                              void* d_out, int out_size, void* d_ws, size_t ws_size,
                              hipStream_t stream) {
    const int*   art_w = (const int*)d_in[0];
    const int*   tpl_w = (const int*)d_in[2];
    const float* amask = (const float*)d_in[4];
    const float* tmask = (const float*)d_in[5];
    const float* emb   = (const float*)d_in[6];
    const float* exp_w = (const float*)d_in[7];
    const float* exp_b = (const float*)d_in[8];
    const float* ref_w = (const float*)d_in[9];
    const float* ref_b = (const float*)d_in[10];
    const float* ff1_w = (const float*)d_in[11];
    const float* ff1_b = (const float*)d_in[12];
    const float* ff2_w = (const float*)d_in[13];
    const float* ff2_b = (const float*)d_in[14];
    float* out = (float*)d_out;

    const size_t art_bytes = (size_t)NB * (NA + 2 * PAD) * ND * 2;
    const size_t tpl_bytes = (size_t)NB * (NT + 2 * PAD) * ND * 2;
    const size_t wpk_bytes = (size_t)10 * 4 * 128 * 768 * 2;

    char* p = (char*)d_ws;
    ushort* art_a = (ushort*)p; p += art_bytes;
    ushort* art_b = (ushort*)p; p += art_bytes;
    ushort* tpl_a = (ushort*)p; p += tpl_bytes;
    ushort* tpl_b = (ushort*)p; p += tpl_bytes;
    ushort* wpack = (ushort*)p; p += wpk_bytes;
    float* a2    = (float*)p; p += (size_t)NB * NA * 4;
    float* t2    = (float*)p; p += (size_t)NB * NT * 4;
    float* rmaxp = (float*)p; p += (size_t)4 * NB * NA * 4;

    pad_zero<<<dim3(128, 4), 256, 0, stream>>>(art_a, art_b, tpl_a, tpl_b);

    repack_w<<<dim3(12, 8, 10), 256, 0, stream>>>(exp_w, ref_w, wpack);

    {
        int n = NB * NA * 32;
        gather_emb_bf16<<<(n + 255) / 256, 256, 0, stream>>>(art_w, emb, art_a, NA, n);
        n = NB * NT * 32;
        gather_emb_bf16<<<(n + 255) / 256, 256, 0, stream>>>(tpl_w, emb, tpl_a, NT, n);
    }

    const int dils[10] = {1, 2, 4, 8, 16, 32, 32, 1, 1, 1};

    ushort* a_cur = art_a; ushort* a_nxt = art_b;
    ushort* t_cur = tpl_a; ushort* t_nxt = tpl_b;
    for (int i = 0; i < 10; ++i) {
        const ushort* wl = wpack + (size_t)i * 4 * 128 * 768;
        const float* bb = (i < 7) ? exp_b + (size_t)i * 512
                                  : ref_b + (size_t)(i - 7) * 512;
        conv_glu_mfma<<<dim3(4, 12, NB), 256, 0, stream>>>(
            a_cur, a_nxt, t_cur, t_nxt, wl, bb, dils[i]);
        ushort* t1 = a_cur; a_cur = a_nxt; a_nxt = t1;
        ushort* t2p = t_cur; t_cur = t_nxt; t_nxt = t2p;
    }
    ushort* art_fin = a_cur;   // 10 swaps -> back to _a
    ushort* tpl_fin = t_cur;

    sumsq_bf16<<<(NB * NA) / 4, 256, 0, stream>>>(art_fin, a2, NA, NB * NA);
    sumsq_bf16<<<(NB * NT) / 4, 256, 0, stream>>>(tpl_fin, t2, NT, NB * NT);

    dist_rowmax_mfma<<<dim3(NA / 128, NB, 4), 256, 0, stream>>>(
        art_fin, tpl_fin, a2, t2, amask, tmask, rmaxp);

    topk_mlp_kernel<<<NB, 256, 0, stream>>>(rmaxp, ff1_w, ff1_b, ff2_w, ff2_b, out);
}

// Round 4
// 421.485 us; speedup vs baseline: 6.8923x; 1.3228x over previous
//
#include <hip/hip_runtime.h>
#include <math.h>

#define NB 16
#define NA 1024
#define NT 512
#define ND 256
#define PAD 32

typedef short bf8_t __attribute__((ext_vector_type(8)));
typedef float f4_t __attribute__((ext_vector_type(4)));

__device__ __forceinline__ float bf2f(ushort u) {
    union { unsigned int i; float f; } v; v.i = ((unsigned int)u) << 16; return v.f;
}
__device__ __forceinline__ ushort f2bf(float f) {
    union { float f; unsigned int i; } v; v.f = f;
    unsigned int x = v.i;
    unsigned int r = (x + 0x7fffu + ((x >> 16) & 1u)) >> 16;
    return (ushort)r;
}
__device__ __forceinline__ void gl_lds16(const void* g, void* l) {
    __builtin_amdgcn_global_load_lds(
        (const __attribute__((address_space(1))) unsigned int*)g,
        (__attribute__((address_space(3))) unsigned int*)l, 16, 0, 0);
}

// Activation layout (k-major, padded): chunk(b, qq, l_phys) at
//   ((b*32 + qq)*Lp + l_phys)*8 ushorts, qq = ch>>3, Lp = L + 64.

// ---------------- zero pad rows -------------------------------------------
__global__ void pad_zero(ushort* __restrict__ art_a, ushort* __restrict__ art_b,
                         ushort* __restrict__ tpl_a, ushort* __restrict__ tpl_b) {
    int y = blockIdx.y;
    ushort* p = (y == 0) ? art_a : (y == 1) ? art_b : (y == 2) ? tpl_a : tpl_b;
    int L = (y < 2) ? NA : NT;
    int Lp = L + 2 * PAD;
    int idx = blockIdx.x * 256 + threadIdx.x;   // 0 .. NB*32*64-1
    int plane = idx >> 6;                       // b*32+qq
    int row_in = idx & 63;
    int slab = (row_in < PAD) ? row_in : L + row_in;
    uint4 z = make_uint4(0, 0, 0, 0);
    *(uint4*)(p + ((size_t)plane * Lp + slab) * 8) = z;
}

// ---------------- embedding gather (fp32 emb -> bf16 k-major) --------------
__global__ void gather_emb_bf16(const int* __restrict__ words,
                                const float* __restrict__ emb,
                                ushort* __restrict__ out, int Lbits, int Lp, int n) {
    int idx = blockIdx.x * 256 + threadIdx.x;
    if (idx >= n) return;
    int L = 1 << Lbits;
    int l = idx & (L - 1);
    int bq = idx >> Lbits;                 // b*32 + qq
    int qq = bq & 31, b = bq >> 5;
    int wd = words[b * L + l];
    const float4* src = (const float4*)(emb + (size_t)wd * ND + qq * 8);
    float4 v0 = src[0], v1 = src[1];
    ushort o[8];
    o[0]=f2bf(v0.x); o[1]=f2bf(v0.y); o[2]=f2bf(v0.z); o[3]=f2bf(v0.w);
    o[4]=f2bf(v1.x); o[5]=f2bf(v1.y); o[6]=f2bf(v1.z); o[7]=f2bf(v1.w);
    *(uint4*)(out + ((size_t)bq * Lp + PAD + l) * 8) = *(uint4*)o;
}

// ---------------- weight repack: fp32 [tap][k][512] -> staged-order bf16 ---
// out chunk (li, cb, tap, kc, qq, c', 8) at
//   (((((li*4+cb)*3 + tap)*8 + kc)*4 + qq)*128 + c')*8
__global__ void __launch_bounds__(256)
repack_w(const float* __restrict__ exp_w, const float* __restrict__ ref_w,
         ushort* __restrict__ wpack) {
    __shared__ float tile[64][65];
    int li = blockIdx.z;
    int gk = blockIdx.x;           // 0..11 (64 k-rows each)
    int gc = blockIdx.y;           // 0..7  (64 cols each)
    const float* src = (li < 7) ? exp_w + (size_t)li * 3 * ND * 512
                                : ref_w + (size_t)(li - 7) * 3 * ND * 512;
    int k0g = gk * 64, c0 = gc * 64;
    int tid = threadIdx.x;
    #pragma unroll
    for (int p = 0; p < 4; ++p) {
        int kr = p * 16 + (tid >> 4);
        int cc = (tid & 15) * 4;
        *(float4*)&tile[kr][cc] =
            *(const float4*)(src + (size_t)(k0g + kr) * 512 + c0 + cc);
    }
    __syncthreads();
    int tap = k0g >> 8, kl0 = k0g & 255, kc0 = kl0 >> 5;
    int ag = c0 >> 8, cb = (c0 & 255) >> 6;
    int kg = tid >> 5, idx = tid & 31;
    int kc = kc0 + (kg >> 2), qq = kg & 3;
    #pragma unroll
    for (int h = 0; h < 2; ++h) {
        int w64 = idx + h * 32;
        int cprime = h * 64 + ag * 32 + idx;
        ushort o[8];
        #pragma unroll
        for (int j = 0; j < 8; ++j) o[j] = f2bf(tile[kg * 8 + j][w64]);
        ushort* d = wpack +
            (((((size_t)(li * 4 + cb) * 3 + tap) * 8 + kc) * 4 + qq) * 128 + cprime) * 8;
        *(uint4*)d = *(uint4*)o;
    }
}

// ---------------- fused conv-GLU-residual, bf16 MFMA (art+tpl fused) --------
__global__ void __launch_bounds__(256, 3)
conv_glu_mfma(const ushort* __restrict__ art_x, ushort* __restrict__ art_y,
              const ushort* __restrict__ tpl_x, ushort* __restrict__ tpl_y,
              const ushort* __restrict__ wp, const float* __restrict__ bias,
              int dil) {
    __shared__ char smem[36864];
    ushort* Als = (ushort*)smem;            // 12 KB: n = qq*192 + r
    ushort* Bls = (ushort*)(smem + 12288);  // 24 KB: n = t*512 + qq*128 + c'
    float* ylds = (float*)smem;             // [128][68] fp32 epilogue

    const int tid = threadIdx.x;
    const int w = tid >> 6, lane = tid & 63;
    const int wm = w >> 1, wn = w & 1;
    const int q = lane >> 4, l15 = lane & 15;

    const int b = blockIdx.z;
    const int plane = blockIdx.y;
    const int cb = blockIdx.x;
    const int b32 = b * 32;

    int Lp, l0;
    const ushort* xb;
    ushort* yb;
    if (plane < 8) {
        Lp = NA + 2 * PAD; l0 = plane * 128;
        xb = art_x; yb = art_y;
    } else {
        Lp = NT + 2 * PAD; l0 = (plane - 8) * 128;
        xb = tpl_x; yb = tpl_y;
    }
    const ushort* wl = wp + (size_t)cb * 98304;   // 3*8*4*128*8

    f4_t acc[4][4];
    #pragma unroll
    for (int i = 0; i < 4; ++i)
        #pragma unroll
        for (int j = 0; j < 4; ++j)
            acc[i][j] = (f4_t){0.f, 0.f, 0.f, 0.f};

    for (int kc = 0; kc < 8; ++kc) {
        // --- stage A_ext: 192 phys rows [l0, l0+192), 4 qq planes ---
        #pragma unroll
        for (int s3 = 0; s3 < 3; ++s3) {
            int s = w + s3 * 4;                // 0..11
            int qq = kc * 4 + s / 3;
            int rphys = l0 + (s % 3) * 64 + lane;
            gl_lds16(xb + ((size_t)(b32 + qq) * Lp + rphys) * 8, Als + s * 512);
        }
        // --- stage B: 3 taps x 4 qq x 128 c', contiguous 1KB per issue ---
        #pragma unroll
        for (int s3 = 0; s3 < 6; ++s3) {
            int s = w + s3 * 4;                // 0..23
            int t = s >> 3, sp = s & 7;
            int qq = sp >> 1, cp0 = (sp & 1) * 64;
            const ushort* g = wl + (((size_t)(t * 8 + kc) * 4 + qq) * 128 + cp0 + lane) * 8;
            gl_lds16(g, Bls + s * 512);
        }
        __syncthreads();

        #pragma unroll
        for (int t = 0; t < 3; ++t) {
            const int sh = (t - 1) * dil;
            bf8_t af[4], bfr[4];
            #pragma unroll
            for (int mt = 0; mt < 4; ++mt)
                af[mt] = *(const bf8_t*)(Als + (q * 192 + 32 + sh + wm * 64 + mt * 16 + l15) * 8);
            #pragma unroll
            for (int nt = 0; nt < 4; ++nt)
                bfr[nt] = *(const bf8_t*)(Bls + (t * 512 + q * 128 + wn * 64 + nt * 16 + l15) * 8);
            #pragma unroll
            for (int mt = 0; mt < 4; ++mt)
                #pragma unroll
                for (int nt = 0; nt < 4; ++nt)
                    acc[mt][nt] = __builtin_amdgcn_mfma_f32_16x16x32_bf16(
                        af[mt], bfr[nt], acc[mt][nt], 0, 0, 0);
        }
        __syncthreads();
    }

    // GLU epilogue into LDS (fp32), row stride 68 (conflict-free b128 reads)
    #pragma unroll
    for (int nt = 0; nt < 2; ++nt) {
        const int cl = wn * 32 + nt * 16 + l15;
        const int chan = cb * 64 + cl;
        const float ba = bias[chan];
        const float bg2 = bias[chan + 256];
        #pragma unroll
        for (int mt = 0; mt < 4; ++mt) {
            #pragma unroll
            for (int r = 0; r < 4; ++r) {
                const int row = wm * 64 + mt * 16 + q * 4 + r;
                float av = acc[mt][nt][r] + ba;
                float gv = acc[mt][nt + 2][r] + bg2;
                ylds[row * 68 + cl] = av / (1.f + __expf(-gv));
            }
        }
    }
    __syncthreads();

    // residual add + bf16 store, k-major coalesced
    #pragma unroll
    for (int p = 0; p < 4; ++p) {
        int u = p * 256 + tid;
        int cl8 = u >> 7;                  // 0..7 plane-chunk within cb
        int row = u & 127;
        size_t go = ((size_t)(b32 + cb * 8 + cl8) * Lp + l0 + PAD + row) * 8;
        ushort xv[8]; *(uint4*)xv = *(const uint4*)(xb + go);
        float4 y0 = *(float4*)&ylds[row * 68 + cl8 * 8];
        float4 y1 = *(float4*)&ylds[row * 68 + cl8 * 8 + 4];
        ushort ov[8];
        ov[0]=f2bf(bf2f(xv[0])+y0.x); ov[1]=f2bf(bf2f(xv[1])+y0.y);
        ov[2]=f2bf(bf2f(xv[2])+y0.z); ov[3]=f2bf(bf2f(xv[3])+y0.w);
        ov[4]=f2bf(bf2f(xv[4])+y1.x); ov[5]=f2bf(bf2f(xv[5])+y1.y);
        ov[6]=f2bf(bf2f(xv[6])+y1.z); ov[7]=f2bf(bf2f(xv[7])+y1.w);
        *(uint4*)(yb + go) = *(uint4*)ov;
    }
}

// ---------------- row-wise sum of squares (k-major) ------------------------
__global__ void sumsq_bf16(const ushort* __restrict__ x, float* __restrict__ out,
                           int L, int Lp) {
    __shared__ float red[4][64];
    int tid = threadIdx.x;
    int r = tid & 63, pg = tid >> 6;
    int row_g = blockIdx.x * 64 + r;
    int b = row_g / L, l = row_g - b * L;
    float s = 0.f;
    #pragma unroll
    for (int j = 0; j < 8; ++j) {
        int qq = pg * 8 + j;
        const ushort* p = x + ((size_t)(b * 32 + qq) * Lp + PAD + l) * 8;
        ushort v[8]; *(uint4*)v = *(const uint4*)p;
        #pragma unroll
        for (int e = 0; e < 8; ++e) { float f = bf2f(v[e]); s += f * f; }
    }
    red[pg][r] = s;
    __syncthreads();
    if (tid < 64)
        out[blockIdx.x * 64 + tid] =
            red[0][tid] + red[1][tid] + red[2][tid] + red[3][tid];
}

// ---------------- distance + exp + row max, bf16 MFMA ----------------------
__global__ void __launch_bounds__(256)
dist_rowmax_mfma(const ushort* __restrict__ art, const ushort* __restrict__ tpl,
                 const float* __restrict__ a2, const float* __restrict__ t2,
                 const float* __restrict__ amask, const float* __restrict__ tmask,
                 float* __restrict__ rmaxp) {
    __shared__ ushort Als[128 * 32];   // n = qq*128 + r
    __shared__ ushort Bls[128 * 32];
    __shared__ float red[2][128];

    const int tid = threadIdx.x;
    const int w = tid >> 6, lane = tid & 63;
    const int wm = w >> 1, wn = w & 1;
    const int q = lane >> 4, l15 = lane & 15;

    const int b = blockIdx.y;
    const int a0 = blockIdx.x * 128;
    const int t0 = blockIdx.z * 128;
    const int b32 = b * 32;
    const int LpA = NA + 2 * PAD, LpT = NT + 2 * PAD;

    float a2v[4][4], amv[4][4];
    #pragma unroll
    for (int mt = 0; mt < 4; ++mt)
        #pragma unroll
        for (int r = 0; r < 4; ++r) {
            int row = a0 + wm * 64 + mt * 16 + q * 4 + r;
            a2v[mt][r] = a2[b * NA + row];
            amv[mt][r] = amask[b * NA + row];
        }

    f4_t acc[4][4];
    #pragma unroll
    for (int i = 0; i < 4; ++i)
        #pragma unroll
        for (int j = 0; j < 4; ++j)
            acc[i][j] = (f4_t){0.f, 0.f, 0.f, 0.f};

    for (int kb = 0; kb < 8; ++kb) {
        #pragma unroll
        for (int s3 = 0; s3 < 2; ++s3) {
            int s = w + s3 * 4;                // 0..7
            int qq = kb * 4 + (s >> 1);
            int r0 = (s & 1) * 64;
            gl_lds16(art + ((size_t)(b32 + qq) * LpA + PAD + a0 + r0 + lane) * 8,
                     Als + s * 512);
            gl_lds16(tpl + ((size_t)(b32 + qq) * LpT + PAD + t0 + r0 + lane) * 8,
                     Bls + s * 512);
        }
        __syncthreads();

        bf8_t af[4], bfr[4];
        #pragma unroll
        for (int mt = 0; mt < 4; ++mt)
            af[mt] = *(const bf8_t*)(Als + (q * 128 + wm * 64 + mt * 16 + l15) * 8);
        #pragma unroll
        for (int nt = 0; nt < 4; ++nt)
            bfr[nt] = *(const bf8_t*)(Bls + (q * 128 + wn * 64 + nt * 16 + l15) * 8);
        #pragma unroll
        for (int mt = 0; mt < 4; ++mt)
            #pragma unroll
            for (int nt = 0; nt < 4; ++nt)
                acc[mt][nt] = __builtin_amdgcn_mfma_f32_16x16x32_bf16(
                    af[mt], bfr[nt], acc[mt][nt], 0, 0, 0);
        __syncthreads();
    }

    float rm[4][4];
    #pragma unroll
    for (int mt = 0; mt < 4; ++mt)
        #pragma unroll
        for (int r = 0; r < 4; ++r) rm[mt][r] = 0.f;

    #pragma unroll
    for (int nt = 0; nt < 4; ++nt) {
        int t = t0 + wn * 64 + nt * 16 + l15;
        float t2v = t2[b * NT + t];
        float tmv = tmask[b * NT + t];
        #pragma unroll
        for (int mt = 0; mt < 4; ++mt)
            #pragma unroll
            for (int r = 0; r < 4; ++r) {
                float d = a2v[mt][r] + t2v - 2.f * acc[mt][nt][r];
                d = fmaxf(d, 0.f);
                float s = __expf(-d) * amv[mt][r] * tmv;
                rm[mt][r] = fmaxf(rm[mt][r], s);
            }
    }
    #pragma unroll
    for (int mt = 0; mt < 4; ++mt)
        #pragma unroll
        for (int r = 0; r < 4; ++r) {
            float v = rm[mt][r];
            #pragma unroll
            for (int off = 1; off < 16; off <<= 1)
                v = fmaxf(v, __shfl_xor(v, off));
            rm[mt][r] = v;
        }
    if (l15 == 0) {
        #pragma unroll
        for (int mt = 0; mt < 4; ++mt)
            #pragma unroll
            for (int r = 0; r < 4; ++r)
                red[wn][wm * 64 + mt * 16 + q * 4 + r] = rm[mt][r];
    }
    __syncthreads();
    if (tid < 128)
        rmaxp[((size_t)blockIdx.z * NB + b) * NA + a0 + tid] =
            fmaxf(red[0][tid], red[1][tid]);
}

// ---------------- top-10 + MLP ---------------------------------------------
__global__ void __launch_bounds__(256)
topk_mlp_kernel(const float* __restrict__ rmaxp,
                const float* __restrict__ ff1_w, const float* __restrict__ ff1_b,
                const float* __restrict__ ff2_w, const float* __restrict__ ff2_b,
                float* __restrict__ out) {
    __shared__ float vals[NA];
    __shared__ float top[10];
    __shared__ float h[10];
    __shared__ float rv[256];
    __shared__ int ri[256];

    int b = blockIdx.x;
    int tid = threadIdx.x;
    for (int i = tid; i < NA; i += 256) {
        float m = rmaxp[(size_t)b * NA + i];
        m = fmaxf(m, rmaxp[((size_t)NB + b) * NA + i]);
        m = fmaxf(m, rmaxp[((size_t)2 * NB + b) * NA + i]);
        m = fmaxf(m, rmaxp[((size_t)3 * NB + b) * NA + i]);
        vals[i] = m;
    }
    __syncthreads();

    for (int it = 0; it < 10; ++it) {
        float best = -1e30f;
        int bi = 0;
        for (int i = tid; i < NA; i += 256) {
            if (vals[i] > best) { best = vals[i]; bi = i; }
        }
        rv[tid] = best; ri[tid] = bi;
        __syncthreads();
        for (int s = 128; s; s >>= 1) {
            if (tid < s) {
                if (rv[tid + s] > rv[tid]) { rv[tid] = rv[tid + s]; ri[tid] = ri[tid + s]; }
            }
            __syncthreads();
        }
        if (tid == 0) { top[it] = rv[0]; vals[ri[0]] = -1e30f; }
        __syncthreads();
    }

    if (tid < 10) {
        float s = ff1_b[tid];
        #pragma unroll
        for (int i = 0; i < 10; ++i) s += top[i] * ff1_w[i * 10 + tid];
        h[tid] = fmaxf(s, 0.f);
    }
    __syncthreads();
    if (tid == 0) {
        float s = ff2_b[0];
        #pragma unroll
        for (int j = 0; j < 10; ++j) s += h[j] * ff2_w[j];
        out[b] = s;
    }
}

// ---------------- launch ----------------------------------------------------
extern "C" void kernel_launch(void* const* d_in, const int* in_sizes, int n_in,
                              void* d_out, int out_size, void* d_ws, size_t ws_size,
                              hipStream_t stream) {
    const int*   art_w = (const int*)d_in[0];
    const int*   tpl_w = (const int*)d_in[2];
    const float* amask = (const float*)d_in[4];
    const float* tmask = (const float*)d_in[5];
    const float* emb   = (const float*)d_in[6];
    const float* exp_w = (const float*)d_in[7];
    const float* exp_b = (const float*)d_in[8];
    const float* ref_w = (const float*)d_in[9];
    const float* ref_b = (const float*)d_in[10];
    const float* ff1_w = (const float*)d_in[11];
    const float* ff1_b = (const float*)d_in[12];
    const float* ff2_w = (const float*)d_in[13];
    const float* ff2_b = (const float*)d_in[14];
    float* out = (float*)d_out;

    const size_t art_bytes = (size_t)NB * 32 * (NA + 2 * PAD) * 8 * 2;
    const size_t tpl_bytes = (size_t)NB * 32 * (NT + 2 * PAD) * 8 * 2;
    const size_t wpk_bytes = (size_t)10 * 4 * 3 * 8 * 4 * 128 * 8 * 2;

    char* p = (char*)d_ws;
    ushort* art_a = (ushort*)p; p += art_bytes;
    ushort* art_b = (ushort*)p; p += art_bytes;
    ushort* tpl_a = (ushort*)p; p += tpl_bytes;
    ushort* tpl_b = (ushort*)p; p += tpl_bytes;
    ushort* wpack = (ushort*)p; p += wpk_bytes;
    float* a2    = (float*)p; p += (size_t)NB * NA * 4;
    float* t2    = (float*)p; p += (size_t)NB * NT * 4;
    float* rmaxp = (float*)p; p += (size_t)4 * NB * NA * 4;

    pad_zero<<<dim3(128, 4), 256, 0, stream>>>(art_a, art_b, tpl_a, tpl_b);
    repack_w<<<dim3(12, 8, 10), 256, 0, stream>>>(exp_w, ref_w, wpack);

    {
        int n = NB * 32 * NA;
        gather_emb_bf16<<<(n + 255) / 256, 256, 0, stream>>>(art_w, emb, art_a, 10, NA + 64, n);
        n = NB * 32 * NT;
        gather_emb_bf16<<<(n + 255) / 256, 256, 0, stream>>>(tpl_w, emb, tpl_a, 9, NT + 64, n);
    }

    const int dils[10] = {1, 2, 4, 8, 16, 32, 32, 1, 1, 1};

    ushort* a_cur = art_a; ushort* a_nxt = art_b;
    ushort* t_cur = tpl_a; ushort* t_nxt = tpl_b;
    for (int i = 0; i < 10; ++i) {
        const ushort* wl = wpack + (size_t)i * 4 * 98304;
        const float* bb = (i < 7) ? exp_b + (size_t)i * 512
                                  : ref_b + (size_t)(i - 7) * 512;
        conv_glu_mfma<<<dim3(4, 12, NB), 256, 0, stream>>>(
            a_cur, a_nxt, t_cur, t_nxt, wl, bb, dils[i]);
        ushort* t1 = a_cur; a_cur = a_nxt; a_nxt = t1;
        ushort* t2p = t_cur; t_cur = t_nxt; t_nxt = t2p;
    }
    ushort* art_fin = a_cur;
    ushort* tpl_fin = t_cur;

    sumsq_bf16<<<(NB * NA) / 64, 256, 0, stream>>>(art_fin, a2, NA, NA + 64);
    sumsq_bf16<<<(NB * NT) / 64, 256, 0, stream>>>(tpl_fin, t2, NT, NT + 64);

    dist_rowmax_mfma<<<dim3(NA / 128, NB, 4), 256, 0, stream>>>(
        art_fin, tpl_fin, a2, t2, amask, tmask, rmaxp);

    topk_mlp_kernel<<<NB, 256, 0, stream>>>(rmaxp, ff1_w, ff1_b, ff2_w, ff2_b, out);
}